// Round 12
// baseline (210.869 us; speedup 1.0000x reference)
//
#include <hip/hip_runtime.h>

#define BB 2
#define SS 2048
#define EE 1024
#define HH 16
#define DD_ 64
#define BH (BB*HH)
#define NQKV (3*EE)
#define MROWS (BB*SS)

typedef _Float16 f16;
typedef _Float16 f16x8 __attribute__((ext_vector_type(8)));
typedef _Float16 f16x4 __attribute__((ext_vector_type(4)));
typedef __fp16 fp16x2 __attribute__((ext_vector_type(2)));
typedef float f32x4 __attribute__((ext_vector_type(4)));
typedef float f32x16 __attribute__((ext_vector_type(16)));

#define MFMA16(a,b,c) __builtin_amdgcn_mfma_f32_16x16x32_f16(a,b,c,0,0,0)
#define MFMA32(a,b,c) __builtin_amdgcn_mfma_f32_32x32x16_f16(a,b,c,0,0,0)
#define EXP2F(x) __builtin_amdgcn_exp2f(x)
#define LOG2E 1.44269504088896f

// gate test -- MUST be the identical expression in every kernel so the
// active-head set is bitwise-consistent.
__device__ __forceinline__ bool head_active(
    const float* gates, const float* imp, const float* thr, int h) {
    const float gs = 1.f / (1.f + __expf(-gates[h] * imp[h]));
    return gs > thr[0];
}

__device__ __forceinline__ void gload16(const void* g, void* l) {
    __builtin_amdgcn_global_load_lds(
        (const __attribute__((address_space(1))) void*)g,
        (__attribute__((address_space(3))) void*)l, 16, 0, 0);
}

__device__ __forceinline__ float vmax16(f32x16 v) {
    float a = fmaxf(v[0], v[1]),  b = fmaxf(v[2], v[3]);
    float c = fmaxf(v[4], v[5]),  d = fmaxf(v[6], v[7]);
    float e = fmaxf(v[8], v[9]),  f = fmaxf(v[10], v[11]);
    float g = fmaxf(v[12], v[13]), h = fmaxf(v[14], v[15]);
    a = fmaxf(a, b); c = fmaxf(c, d); e = fmaxf(e, f); g = fmaxf(g, h);
    return fmaxf(fmaxf(a, c), fmaxf(e, g));
}

// ---------------------------------------------------------------------------
// fp32 -> f16 one-shot convert: x (4M), qkv_w (3M), out_w (1M) floats.
// qkv_w rows of INACTIVE heads are skipped. Block 0 zeroes vmean.
// ---------------------------------------------------------------------------
#define NX4  1048576
#define NW14  786432
#define NW24  262144
__global__ __launch_bounds__(256) void cvt_kernel(
    const float* __restrict__ x, const float* __restrict__ w1,
    const float* __restrict__ w2, f16* __restrict__ x16,
    f16* __restrict__ w116, f16* __restrict__ w216,
    const float* __restrict__ gates, const float* __restrict__ imp,
    const float* __restrict__ thr, float* __restrict__ vmean)
{
    if (blockIdx.x == 0) {                 // zero vmean: BH*DD_ = 2048 floats
        const float4 z = {0.f, 0.f, 0.f, 0.f};
        ((float4*)vmean)[threadIdx.x*2]     = z;
        ((float4*)vmean)[threadIdx.x*2 + 1] = z;
    }
    const int i = blockIdx.x * 256 + threadIdx.x;
    const float* src; f16* dst; int off;
    if (i < NX4)              { src = x;  dst = x16;  off = i; }
    else if (i < NX4 + NW14)  {
        src = w1; dst = w116; off = i - NX4;
        const int row = off >> 8;              // 4 floats/thread, 1024/row
        if (!head_active(gates, imp, thr, (row & 1023) >> 6)) return;
    }
    else                      { src = w2; dst = w216; off = i - NX4 - NW14; }
    float4 v = ((const float4*)src)[off];
    f16x4 h = { (f16)v.x, (f16)v.y, (f16)v.z, (f16)v.w };
    *(f16x4*)(dst + 4*(size_t)off) = h;
}

// ---------------------------------------------------------------------------
// QKV GEMM v5 (verified r11): head-granular gating + 2-phase dbuf staging +
// fused v-transpose via LDS bounce (coalesced 256B runs along s).
// Block = 128 rows x 64 cols (one head block), 4 waves, BK=64. LDS 48 KB.
// Grid (rows=32 in x, cols=48 in y): id%8 = x%8 -> XCD-uniform.
// ---------------------------------------------------------------------------
__global__ __launch_bounds__(256) void qkv_gemm_kernel(
    const f16* __restrict__ x, const f16* __restrict__ w,
    const float* __restrict__ bias, const float* __restrict__ gates,
    const float* __restrict__ imp, const float* __restrict__ thr,
    f16* __restrict__ q16, f16* __restrict__ k16,
    f16* __restrict__ vtb, float* __restrict__ vmean)
{
    __shared__ f16 As[2][128*64];
    __shared__ f16 Bs[2][64*64];
    const int tid  = threadIdx.x;
    const int wave = tid >> 6, lane = tid & 63;
    const int quad = lane >> 4, l15 = lane & 15;
    const int m0 = blockIdx.x << 7;        // rows (fast dim, uniform mod 8)
    const int n0 = blockIdx.y << 6;        // one 64-col head block
    const int which = n0 >> 10;
    const int h     = (n0 & 1023) >> 6;
    if (!head_active(gates, imp, thr, h)) return;

#define QSTAGE(K0, B) do {                                                   \
    _Pragma("unroll")                                                        \
    for (int u = 0; u < 4; ++u) {                                            \
        const int s_ = tid + (u << 8);                                       \
        const int r_ = s_ >> 3;                                              \
        const int sc_ = ((s_ & 7) ^ (r_ & 7)) << 3;                          \
        gload16(x + (size_t)(m0 + r_)*EE + (K0) + sc_, &As[B][s_ << 3]);     \
    }                                                                        \
    _Pragma("unroll")                                                        \
    for (int u = 0; u < 2; ++u) {                                            \
        const int s_ = tid + (u << 8);                                       \
        const int r_ = s_ >> 3;                                              \
        const int sc_ = ((s_ & 7) ^ (r_ & 7)) << 3;                          \
        gload16(w + (size_t)(n0 + r_)*EE + (K0) + sc_, &Bs[B][s_ << 3]);     \
    } } while (0)

    f32x4 acc[2][4];
#pragma unroll
    for (int i = 0; i < 2; ++i)
#pragma unroll
        for (int j = 0; j < 4; ++j) acc[i][j] = (f32x4){0.f,0.f,0.f,0.f};

    QSTAGE(0, 0);                          // prologue: K-tile 0 -> buf 0
    int cur = 0;
    for (int t = 0; t < 16; ++t) {
        __syncthreads();                   // stage of tile t complete (vmcnt0)
        if (t < 15) QSTAGE((t + 1) << 6, cur ^ 1);
#pragma unroll
        for (int ks = 0; ks < 2; ++ks) {
            f16x8 af[2], bf[4];
#pragma unroll
            for (int i = 0; i < 2; ++i) {
                const int r = wave*32 + i*16 + l15;
                af[i] = *(const f16x8*)&As[cur][(r << 6) + ((((ks<<2)+quad) ^ (l15 & 7)) << 3)];
            }
#pragma unroll
            for (int j = 0; j < 4; ++j) {
                const int r = j*16 + l15;
                bf[j] = *(const f16x8*)&Bs[cur][(r << 6) + ((((ks<<2)+quad) ^ (l15 & 7)) << 3)];
            }
#pragma unroll
            for (int i = 0; i < 2; ++i)
#pragma unroll
                for (int j = 0; j < 4; ++j)
                    acc[i][j] = MFMA16(af[i], bf[j], acc[i][j]);
        }
        cur ^= 1;
    }
#undef QSTAGE

    float bv[4];
#pragma unroll
    for (int j = 0; j < 4; ++j) bv[j] = bias[n0 + j*16 + l15];

    if (which == 2) {
        // ---- fused v-transpose via LDS bounce ----
        __syncthreads();                   // all waves done with K-loop LDS
        f16* T = &As[0][0];                // [64 d][136 s-padded], 17.4 KB
        const int b  = m0 >> 11, s0 = m0 & (SS - 1);
        const int bhv = b*HH + h;
        float colsum[4];
#pragma unroll
        for (int j = 0; j < 4; ++j) {
            colsum[j] = 0.f;
#pragma unroll
            for (int i = 0; i < 2; ++i) {
                f16x4 pk;
#pragma unroll
                for (int reg = 0; reg < 4; ++reg) {
                    const f16 hv = (f16)(acc[i][j][reg] + bv[j]);
                    pk[reg] = hv;
                    colsum[j] += (float)hv;   // f16-rounded, matches vtrans
                }
                const int m_loc = wave*32 + i*16 + quad*4;
                *(f16x4*)&T[(j*16 + l15)*136 + m_loc] = pk;
            }
        }
#pragma unroll
        for (int j = 0; j < 4; ++j) {
            float c = colsum[j];
            c += __shfl_xor(c, 16, 64);       // reduce over quads
            c += __shfl_xor(c, 32, 64);
            if (quad == 0)
                atomicAdd(vmean + bhv*DD_ + j*16 + l15, c * (1.f / SS));
        }
        __syncthreads();
        const int d = tid >> 2, ch = (tid & 3) << 5;   // 32 s-elems/thread
        f16* dp = vtb + ((size_t)(bhv*DD_ + d))*SS + s0 + ch;
#pragma unroll
        for (int u = 0; u < 4; ++u)
            *(f16x8*)(dp + u*8) = *(const f16x8*)&T[d*136 + ch + u*8];
        return;
    }

    const float scale = (which == 0) ? LOG2E : 1.f;
    f16* __restrict__ dst = (which == 0) ? q16 : k16;
#pragma unroll
    for (int i = 0; i < 2; ++i) {
#pragma unroll
        for (int reg = 0; reg < 4; ++reg) {
            const int m = m0 + wave*32 + i*16 + quad*4 + reg;
            const int b = m >> 11, s = m & (SS - 1);
            f16* rowp = dst + (((size_t)(b*HH + h))*SS + s)*DD_ + l15;
#pragma unroll
            for (int j = 0; j < 4; ++j)
                rowp[j*16] = (f16)((acc[i][j][reg] + bv[j]) * scale);
        }
    }
}

// ---------------------------------------------------------------------------
// Flash attention v13: PARTS=8 occupancy push. r11 analysis: attn is
// grid-occupancy-limited (3 active blocks/CU = 3 waves/SIMD; throughput
// model ~2040 cyc/tile/CU at 4 resident, linear in resident blocks), and
// opart partials are L3-resident (r4: WRITE_SIZE 34MB << 64MB logical), so
// extra key-parts cost L3 bandwidth, not HBM. KPL=3: 16qc x 8kp x 32bh ->
// 1536 active blocks ~ 6/CU; __launch_bounds__(256,5) lets LDS (32KB x 5 =
// 160KB exactly) admit 5 resident blocks/CU (was 4).
// Core loop unchanged (verified r6-r11): 2-phase dbuf, prefetch t+1,
// defer-max, register P^T reshape, setprio, XCD-uniform grid.
// ---------------------------------------------------------------------------
template<int KPL>
__global__ __launch_bounds__(256, 5) void attn_kernel(
    const f16* __restrict__ q16, const f16* __restrict__ k16,
    const f16* __restrict__ vt,
    const float* __restrict__ gates, const float* __restrict__ imp,
    const float* __restrict__ thr,
    float* __restrict__ opart, float* __restrict__ mlpart)
{
    constexpr int NT = 1 << (5 - KPL);     // 64-key tiles per part
    __shared__ f16 Ks[2][64*64];
    __shared__ f16 Vs[2][64*64];
    const int tid  = threadIdx.x;
    const int wave = tid >> 6, lane = tid & 63;
    const int l31 = lane & 31, hi = lane >> 5, l7 = lane & 7;
    const int bh = blockIdx.y;             // SLOW dim: id%8 independent of bh
    const int kp = blockIdx.x & ((1 << KPL) - 1);
    const int qc = blockIdx.x >> KPL;      // 0..15
    const int q0 = qc << 7;                // 128 q-rows/block
    const int k0 = kp << (11 - KPL);       // keys/part = SS>>KPL

    if (!head_active(gates, imp, thr, bh & (HH - 1))) return;

    const f16* qb = q16 + (size_t)bh * SS * DD_;
    const f16* kb = k16 + (size_t)bh * SS * DD_;
    const f16* vb = vt  + (size_t)bh * DD_ * SS;

    // staging (r6 pattern): thread owns chunks tid, tid+256 of each tile
    const int r0 = tid >> 3, r1 = r0 + 32, cc = tid & 7;
    const int sc0 = (cc ^ (r0 & 7)) << 3;
    const int sc1 = (cc ^ (r1 & 7)) << 3;

    // prologue: stage tile 0 into buffer 0 (flies under Q-frag loads)
    gload16(kb + (size_t)(k0 + r0)*DD_ + sc0, &Ks[0][tid << 3]);
    gload16(kb + (size_t)(k0 + r1)*DD_ + sc1, &Ks[0][(tid + 256) << 3]);
    gload16(vb + (size_t)r0*SS + k0 + sc0,    &Vs[0][tid << 3]);
    gload16(vb + (size_t)r1*SS + k0 + sc1,    &Vs[0][(tid + 256) << 3]);

    f16x8 qf[4];
#pragma unroll
    for (int ks = 0; ks < 4; ++ks)
        qf[ks] = *(const f16x8*)(qb +
            (size_t)(q0 + wave*32 + l31)*DD_ + ks*16 + hi*8);

    f32x16 accO[2];
#pragma unroll
    for (int dt = 0; dt < 2; ++dt)
#pragma unroll
        for (int r = 0; r < 16; ++r) accO[dt][r] = 0.f;
    float M = 0.f;
    float lsum = 0.f;

    int cur = 0;
    for (int t = 0; t < NT; ++t) {
        const int kt = k0 + (t << 6);
        __syncthreads();               // stage of tile t complete (vmcnt0)
        if (t < NT - 1) {              // prefetch tile t+1 into other buffer
            const int kn = kt + 64;
            gload16(kb + (size_t)(kn + r0)*DD_ + sc0, &Ks[cur^1][tid << 3]);
            gload16(kb + (size_t)(kn + r1)*DD_ + sc1, &Ks[cur^1][(tid + 256) << 3]);
            gload16(vb + (size_t)r0*SS + kn + sc0,    &Vs[cur^1][tid << 3]);
            gload16(vb + (size_t)r1*SS + kn + sc1,    &Vs[cur^1][(tid + 256) << 3]);
        }

        // S^T[key][qrow] - M: A = K rows, B = Q^T, C init = -M
        f32x16 accS[2];
        const float negM = -M;
#pragma unroll
        for (int mt = 0; mt < 2; ++mt)
#pragma unroll
            for (int r = 0; r < 16; ++r) accS[mt][r] = negM;
        __builtin_amdgcn_s_setprio(1);
#pragma unroll
        for (int ks = 0; ks < 4; ++ks)
#pragma unroll
            for (int mt = 0; mt < 2; ++mt) {
                f16x8 kf = *(const f16x8*)&Ks[cur][((mt*32 + l31) << 6) +
                                                  ((((ks<<1)+hi) ^ l7) << 3)];
                accS[mt] = MFMA32(kf, qf[ks], accS[mt]);
            }
        __builtin_amdgcn_s_setprio(0);

        // defer-max
        const float mxl = fmaxf(vmax16(accS[0]), vmax16(accS[1]));
        if (!__all(mxl <= 8.f)) {
            float mx = mxl;
            mx = fmaxf(mx, __shfl_xor(mx, 1, 64));
            mx = fmaxf(mx, __shfl_xor(mx, 2, 64));
            mx = fmaxf(mx, __shfl_xor(mx, 4, 64));
            mx = fmaxf(mx, __shfl_xor(mx, 8, 64));
            mx = fmaxf(mx, __shfl_xor(mx, 16, 64));
            mx = fmaxf(mx, __shfl_xor(mx, 32, 64));
            const float alpha = EXP2F(-mx);
            M += mx;
            lsum *= alpha;
#pragma unroll
            for (int r = 0; r < 16; ++r) { accO[0][r] *= alpha; accO[1][r] *= alpha; }
#pragma unroll
            for (int mt = 0; mt < 2; ++mt)
#pragma unroll
                for (int r = 0; r < 16; ++r) accS[mt][r] -= mx;
        }

        // p = exp2(accS); per-row sums
        float rs[2];
#pragma unroll
        for (int mt = 0; mt < 2; ++mt) {
            float t0 = 0.f, t1 = 0.f, t2 = 0.f, t3 = 0.f;
#pragma unroll
            for (int r = 0; r < 16; r += 4) {
                float p0 = EXP2F(accS[mt][r+0]); accS[mt][r+0] = p0; t0 += p0;
                float p1 = EXP2F(accS[mt][r+1]); accS[mt][r+1] = p1; t1 += p1;
                float p2 = EXP2F(accS[mt][r+2]); accS[mt][r+2] = p2; t2 += p2;
                float p3 = EXP2F(accS[mt][r+3]); accS[mt][r+3] = p3; t3 += p3;
            }
            rs[mt] = (t0 + t1) + (t2 + t3);
        }
        float sum = rs[0] + rs[1];
        sum += __shfl_xor(sum, 32, 64);
        lsum += sum;

        // pack P to f16x2 pairs
        int pki[2][8];
#pragma unroll
        for (int mt = 0; mt < 2; ++mt)
#pragma unroll
            for (int t2_ = 0; t2_ < 8; ++t2_) {
                union { fp16x2 h; int i; } c;
                c.h = __builtin_amdgcn_cvt_pkrtz(accS[mt][2*t2_], accS[mt][2*t2_+1]);
                pki[mt][t2_] = c.i;
            }

        // PV: O^T = V^T * P^T (r8-verified B-frag mapping)
#pragma unroll
        for (int ks = 0; ks < 4; ++ks) {
            const int mt = ks >> 1;
            const int bidx = (ks & 1) << 2;
            const int a0 = pki[mt][bidx+0], a1 = pki[mt][bidx+1];
            const int b0 = pki[mt][bidx+2], b1 = pki[mt][bidx+3];
            const int s0 = hi ? a0 : b0;
            const int s1 = hi ? a1 : b1;
            const int r0x = __shfl_xor(s0, 32, 64);
            const int r1x = __shfl_xor(s1, 32, 64);
            union { int i[4]; f16x8 h; } u;
            u.i[0] = hi ? r0x : a0;
            u.i[1] = hi ? r1x : a1;
            u.i[2] = hi ? b0 : r0x;
            u.i[3] = hi ? b1 : r1x;
            f16x8 pf = u.h;
            __builtin_amdgcn_s_setprio(1);
#pragma unroll
            for (int dt = 0; dt < 2; ++dt) {
                f16x8 vf = *(const f16x8*)&Vs[cur][((dt*32 + l31) << 6) +
                                                  ((((ks<<1)+hi) ^ l7) << 3)];
                accO[dt] = MFMA32(vf, pf, accO[dt]);
            }
            __builtin_amdgcn_s_setprio(0);
        }
        cur ^= 1;
    }

    // store fp32 partials: O^T (un-normalized), M, lsum per q-row
    {
        const int s = q0 + wave*32 + l31;
        const size_t rowi = (size_t)kp*BH*SS + (size_t)bh*SS + s;
        float* ob = opart + (rowi << 6);
#pragma unroll
        for (int dt = 0; dt < 2; ++dt)
#pragma unroll
            for (int g = 0; g < 4; ++g) {
                const int d0 = dt*32 + 8*g + 4*hi;
                float4 o = { accO[dt][4*g+0], accO[dt][4*g+1],
                             accO[dt][4*g+2], accO[dt][4*g+3] };
                *(float4*)(ob + d0) = o;
            }
        if (hi == 0) {
            float2 ml = { M, lsum };
            *(float2*)(mlpart + rowi*2) = ml;
        }
    }
}

// ---------------------------------------------------------------------------
// Combine PARTS key-part partials. Inactive heads: return WITHOUT writing.
// ---------------------------------------------------------------------------
template<int PARTS>
__global__ __launch_bounds__(256) void combine_kernel(
    const float* __restrict__ opart, const float* __restrict__ mlpart,
    const float* __restrict__ vmean,
    const float* __restrict__ gates, const float* __restrict__ imp,
    const float* __restrict__ thr, f16* __restrict__ aout)
{
    const int t = blockIdx.x * 256 + threadIdx.x;  // 0 .. 262143
    const int row = t >> 2;                        // bh*SS + s
    const int dc = (t & 3) << 4;
    const int bh = row >> 11, s = row & (SS - 1);
    const int b = bh >> 4, h = bh & (HH - 1);

    if (!head_active(gates, imp, thr, h)) return;  // aout region never read

    f16* op = aout + ((size_t)(b*SS + s))*EE + h*DD_ + dc;
    float2 ml[PARTS];
    float mx = -1.0e30f;
#pragma unroll
    for (int p = 0; p < PARTS; ++p) {
        ml[p] = ((const float2*)mlpart)[(size_t)p*BH*SS + row];
        mx = fmaxf(mx, ml[p].x);
    }
    float a[PARTS], denom = 0.f;
#pragma unroll
    for (int p = 0; p < PARTS; ++p) {
        a[p] = EXP2F(ml[p].x - mx);
        denom += ml[p].y * a[p];
    }
    const float inv = 1.f / denom;
    const float* o0 = opart + ((size_t)row << 6) + dc;
#pragma unroll
    for (int j = 0; j < 4; ++j) {
        float4 acc = {0.f, 0.f, 0.f, 0.f};
#pragma unroll
        for (int p = 0; p < PARTS; ++p) {
            float4 v = ((const float4*)(o0 + (size_t)p*BH*SS*DD_))[j];
            acc.x += v.x*a[p]; acc.y += v.y*a[p];
            acc.z += v.z*a[p]; acc.w += v.w*a[p];
        }
        float4 vm = *(const float4*)(vmean + bh*DD_ + dc + 4*j);
        f16x4 o = { (f16)(acc.x*inv + vm.x), (f16)(acc.y*inv + vm.y),
                    (f16)(acc.z*inv + vm.z), (f16)(acc.w*inv + vm.w) };
        *(f16x4*)(op + 4*j) = o;
    }
}

// ---------------------------------------------------------------------------
// Output GEMM v3 (verified r11): K-tile skip + 2-phase dbuf over the active
// K-tile list, 64-row M-blocks (512 blocks = 2/CU). LDS 48 KB.
// ---------------------------------------------------------------------------
__global__ __launch_bounds__(256) void out_gemm_kernel(
    const f16* __restrict__ a, const f16* __restrict__ w,
    const float* __restrict__ bias, const float* __restrict__ gates,
    const float* __restrict__ imp, const float* __restrict__ thr,
    float* __restrict__ y)
{
    __shared__ f16 As[2][64*64];
    __shared__ f16 Bs[2][128*64];
    const int tid  = threadIdx.x;
    const int wave = tid >> 6, lane = tid & 63;
    const int quad = lane >> 4, l15 = lane & 15;
    const int wm = wave & 1, wn = wave >> 1;
    const int m0 = blockIdx.x << 6;        // 64-row block (fast, XCD-uniform)
    const int n0 = blockIdx.y << 7;

    unsigned hmask = 0;
#pragma unroll
    for (int h = 0; h < HH; ++h)
        if (head_active(gates, imp, thr, h)) hmask |= (1u << h);

#define OSTAGE(K0, B) do {                                                   \
    _Pragma("unroll")                                                        \
    for (int u = 0; u < 2; ++u) {          /* As: 64x64 = 8 KB */            \
        const int s_ = tid + (u << 8);                                       \
        const int r_ = s_ >> 3;                                              \
        const int sc_ = ((s_ & 7) ^ (r_ & 7)) << 3;                          \
        gload16(a + (size_t)(m0 + r_)*EE + (K0) + sc_, &As[B][s_ << 3]);     \
    }                                                                        \
    _Pragma("unroll")                                                        \
    for (int u = 0; u < 4; ++u) {          /* Bs: 128x64 = 16 KB */          \
        const int s_ = tid + (u << 8);                                       \
        const int r_ = s_ >> 3;                                              \
        const int sc_ = ((s_ & 7) ^ (r_ & 7)) << 3;                          \
        gload16(w + (size_t)(n0 + r_)*EE + (K0) + sc_, &Bs[B][s_ << 3]);     \
    } } while (0)

    f32x4 acc[2][4];
#pragma unroll
    for (int i = 0; i < 2; ++i)
#pragma unroll
        for (int j = 0; j < 4; ++j) acc[i][j] = (f32x4){0.f,0.f,0.f,0.f};

    unsigned m = hmask;
    int kcur = m ? (__ffs(m) - 1) : -1;
    if (m) m &= m - 1;
    if (kcur >= 0) OSTAGE(kcur << 6, 0);
    int cur = 0;
    while (kcur >= 0) {
        const int knext = m ? (__ffs(m) - 1) : -1;
        if (m) m &= m - 1;
        __syncthreads();                   // stage into cur complete (vmcnt0)
        if (knext >= 0) OSTAGE(knext << 6, cur ^ 1);
#pragma unroll
        for (int ks = 0; ks < 2; ++ks) {
            f16x8 af[2], bf[4];
#pragma unroll
            for (int i = 0; i < 2; ++i) {
                const int r = wm*32 + i*16 + l15;
                af[i] = *(const f16x8*)&As[cur][(r << 6) + ((((ks<<2)+quad) ^ (l15 & 7)) << 3)];
            }
#pragma unroll
            for (int j = 0; j < 4; ++j) {
                const int r = wn*64 + j*16 + l15;
                bf[j] = *(const f16x8*)&Bs[cur][(r << 6) + ((((ks<<2)+quad) ^ (l15 & 7)) << 3)];
            }
#pragma unroll
            for (int i = 0; i < 2; ++i)
#pragma unroll
                for (int j = 0; j < 4; ++j)
                    acc[i][j] = MFMA16(af[i], bf[j], acc[i][j]);
        }
        cur ^= 1;
        kcur = knext;
    }
#undef OSTAGE

    float bv[4];
#pragma unroll
    for (int j = 0; j < 4; ++j) bv[j] = bias[n0 + wn*64 + j*16 + l15];
#pragma unroll
    for (int i = 0; i < 2; ++i) {
#pragma unroll
        for (int reg = 0; reg < 4; ++reg) {
            const int m2 = m0 + wm*32 + i*16 + quad*4 + reg;
#pragma unroll
            for (int j = 0; j < 4; ++j)
                y[(size_t)m2*EE + n0 + wn*64 + j*16 + l15] = acc[i][j][reg] + bv[j];
        }
    }
}

// ---------------------------------------------------------------------------
extern "C" void kernel_launch(void* const* d_in, const int* in_sizes, int n_in,
                              void* d_out, int out_size, void* d_ws, size_t ws_size,
                              hipStream_t stream)
{
    const float* x      = (const float*)d_in[0];
    const float* qkv_w  = (const float*)d_in[1];
    const float* qkv_b  = (const float*)d_in[2];
    const float* out_w  = (const float*)d_in[3];
    const float* out_b  = (const float*)d_in[4];
    const float* gates  = (const float*)d_in[5];
    const float* imp    = (const float*)d_in[6];
    const float* thr    = (const float*)d_in[7];
    float* out = (float*)d_out;

    const size_t TSZ = (size_t)BH * SS * DD_;
    f16* x16  = (f16*)d_ws;
    f16* w116 = x16 + (size_t)MROWS * EE;
    f16* w216 = w116 + (size_t)NQKV * EE;
    f16* q16  = w216 + (size_t)EE * EE;
    f16* k16  = q16 + TSZ;
    f16* vtb  = k16 + TSZ;                 // v16 eliminated (fused vtrans)
    f16* aout = vtb + TSZ;
    float* vmean  = (float*)(aout + TSZ);               // BH*DD_ floats
    float* opart  = vmean + (size_t)BH * DD_;

    // key-split: 8 parts if workspace allows (occupancy: 1536 active blocks
    // ~6/CU; partials are L3-resident so extra parts cost L3 not HBM BW),
    // else 4, else 2.
    const size_t base_bytes = (size_t)((char*)opart - (char*)d_ws);
    const size_t per_part   = (size_t)BH*SS*DD_*4 + (size_t)BH*SS*2*4;
    const int parts = (ws_size >= base_bytes + 8*per_part) ? 8 :
                      (ws_size >= base_bytes + 4*per_part) ? 4 : 2;

    float* mlpart = opart + (size_t)parts*BH*SS*DD_;

    cvt_kernel<<<(NX4 + NW14 + NW24) / 256, 256, 0, stream>>>(
        x, qkv_w, out_w, x16, w116, w216, gates, imp, thr, vmean);

    dim3 g1(MROWS/128, NQKV/64);    // 32 x 48: rows fast (XCD-uniform)
    qkv_gemm_kernel<<<g1, 256, 0, stream>>>(x16, w116, qkv_b, gates, imp, thr,
                                            q16, k16, vtb, vmean);

    // x = (qc,kp) fast -> id%8 uniform over XCDs; bh SLOW
    dim3 g2a(16 * parts, BH);
    if (parts == 8)
        attn_kernel<3><<<g2a, 256, 0, stream>>>(q16, k16, vtb, gates, imp, thr,
                                                opart, mlpart);
    else if (parts == 4)
        attn_kernel<2><<<g2a, 256, 0, stream>>>(q16, k16, vtb, gates, imp, thr,
                                                opart, mlpart);
    else
        attn_kernel<1><<<g2a, 256, 0, stream>>>(q16, k16, vtb, gates, imp, thr,
                                                opart, mlpart);

    if (parts == 8)
        combine_kernel<8><<<(BH*SS*4)/256, 256, 0, stream>>>(
            opart, mlpart, vmean, gates, imp, thr, aout);
    else if (parts == 4)
        combine_kernel<4><<<(BH*SS*4)/256, 256, 0, stream>>>(
            opart, mlpart, vmean, gates, imp, thr, aout);
    else
        combine_kernel<2><<<(BH*SS*4)/256, 256, 0, stream>>>(
            opart, mlpart, vmean, gates, imp, thr, aout);

    dim3 g3(MROWS/64, EE/128);      // 64 x 8: 64-row blocks, rows fast
    out_gemm_kernel<<<g3, 256, 0, stream>>>(aout, w216, out_b, gates, imp, thr,
                                            out);
}

// Round 13
// 157.563 us; speedup vs baseline: 1.3383x; 1.3383x over previous
//
#include <hip/hip_runtime.h>

#define BB 2
#define SS 2048
#define EE 1024
#define HH 16
#define DD_ 64
#define BH (BB*HH)
#define NQKV (3*EE)
#define MROWS (BB*SS)

typedef _Float16 f16;
typedef _Float16 f16x8 __attribute__((ext_vector_type(8)));
typedef _Float16 f16x4 __attribute__((ext_vector_type(4)));
typedef __fp16 fp16x2 __attribute__((ext_vector_type(2)));
typedef float f32x4 __attribute__((ext_vector_type(4)));
typedef float f32x16 __attribute__((ext_vector_type(16)));

#define MFMA16(a,b,c) __builtin_amdgcn_mfma_f32_16x16x32_f16(a,b,c,0,0,0)
#define MFMA32(a,b,c) __builtin_amdgcn_mfma_f32_32x32x16_f16(a,b,c,0,0,0)
#define EXP2F(x) __builtin_amdgcn_exp2f(x)
#define LOG2E 1.44269504088896f

// gate test -- MUST be the identical expression in every kernel so the
// active-head set is bitwise-consistent.
__device__ __forceinline__ bool head_active(
    const float* gates, const float* imp, const float* thr, int h) {
    const float gs = 1.f / (1.f + __expf(-gates[h] * imp[h]));
    return gs > thr[0];
}

__device__ __forceinline__ void gload16(const void* g, void* l) {
    __builtin_amdgcn_global_load_lds(
        (const __attribute__((address_space(1))) void*)g,
        (__attribute__((address_space(3))) void*)l, 16, 0, 0);
}

__device__ __forceinline__ float vmax16(f32x16 v) {
    float a = fmaxf(v[0], v[1]),  b = fmaxf(v[2], v[3]);
    float c = fmaxf(v[4], v[5]),  d = fmaxf(v[6], v[7]);
    float e = fmaxf(v[8], v[9]),  f = fmaxf(v[10], v[11]);
    float g = fmaxf(v[12], v[13]), h = fmaxf(v[14], v[15]);
    a = fmaxf(a, b); c = fmaxf(c, d); e = fmaxf(e, f); g = fmaxf(g, h);
    return fmaxf(fmaxf(a, c), fmaxf(e, g));
}

// ---------------------------------------------------------------------------
// fp32 -> f16 one-shot convert: x (4M), qkv_w (3M), out_w (1M) floats.
// qkv_w rows of INACTIVE heads are skipped. Block 0 zeroes vmean.
// ---------------------------------------------------------------------------
#define NX4  1048576
#define NW14  786432
#define NW24  262144
__global__ __launch_bounds__(256) void cvt_kernel(
    const float* __restrict__ x, const float* __restrict__ w1,
    const float* __restrict__ w2, f16* __restrict__ x16,
    f16* __restrict__ w116, f16* __restrict__ w216,
    const float* __restrict__ gates, const float* __restrict__ imp,
    const float* __restrict__ thr, float* __restrict__ vmean)
{
    if (blockIdx.x == 0) {                 // zero vmean: BH*DD_ = 2048 floats
        const float4 z = {0.f, 0.f, 0.f, 0.f};
        ((float4*)vmean)[threadIdx.x*2]     = z;
        ((float4*)vmean)[threadIdx.x*2 + 1] = z;
    }
    const int i = blockIdx.x * 256 + threadIdx.x;
    const float* src; f16* dst; int off;
    if (i < NX4)              { src = x;  dst = x16;  off = i; }
    else if (i < NX4 + NW14)  {
        src = w1; dst = w116; off = i - NX4;
        const int row = off >> 8;              // 4 floats/thread, 1024/row
        if (!head_active(gates, imp, thr, (row & 1023) >> 6)) return;
    }
    else                      { src = w2; dst = w216; off = i - NX4 - NW14; }
    float4 v = ((const float4*)src)[off];
    f16x4 h = { (f16)v.x, (f16)v.y, (f16)v.z, (f16)v.w };
    *(f16x4*)(dst + 4*(size_t)off) = h;
}

// ---------------------------------------------------------------------------
// QKV GEMM v5 (verified r11): head-granular gating + 2-phase dbuf staging +
// fused v-transpose via LDS bounce (coalesced 256B runs along s).
// Block = 128 rows x 64 cols (one head block), 4 waves, BK=64. LDS 48 KB.
// Grid (rows=32 in x, cols=48 in y): id%8 = x%8 -> XCD-uniform.
// ---------------------------------------------------------------------------
__global__ __launch_bounds__(256) void qkv_gemm_kernel(
    const f16* __restrict__ x, const f16* __restrict__ w,
    const float* __restrict__ bias, const float* __restrict__ gates,
    const float* __restrict__ imp, const float* __restrict__ thr,
    f16* __restrict__ q16, f16* __restrict__ k16,
    f16* __restrict__ vtb, float* __restrict__ vmean)
{
    __shared__ f16 As[2][128*64];
    __shared__ f16 Bs[2][64*64];
    const int tid  = threadIdx.x;
    const int wave = tid >> 6, lane = tid & 63;
    const int quad = lane >> 4, l15 = lane & 15;
    const int m0 = blockIdx.x << 7;        // rows (fast dim, uniform mod 8)
    const int n0 = blockIdx.y << 6;        // one 64-col head block
    const int which = n0 >> 10;
    const int h     = (n0 & 1023) >> 6;
    if (!head_active(gates, imp, thr, h)) return;

#define QSTAGE(K0, B) do {                                                   \
    _Pragma("unroll")                                                        \
    for (int u = 0; u < 4; ++u) {                                            \
        const int s_ = tid + (u << 8);                                       \
        const int r_ = s_ >> 3;                                              \
        const int sc_ = ((s_ & 7) ^ (r_ & 7)) << 3;                          \
        gload16(x + (size_t)(m0 + r_)*EE + (K0) + sc_, &As[B][s_ << 3]);     \
    }                                                                        \
    _Pragma("unroll")                                                        \
    for (int u = 0; u < 2; ++u) {                                            \
        const int s_ = tid + (u << 8);                                       \
        const int r_ = s_ >> 3;                                              \
        const int sc_ = ((s_ & 7) ^ (r_ & 7)) << 3;                          \
        gload16(w + (size_t)(n0 + r_)*EE + (K0) + sc_, &Bs[B][s_ << 3]);     \
    } } while (0)

    f32x4 acc[2][4];
#pragma unroll
    for (int i = 0; i < 2; ++i)
#pragma unroll
        for (int j = 0; j < 4; ++j) acc[i][j] = (f32x4){0.f,0.f,0.f,0.f};

    QSTAGE(0, 0);                          // prologue: K-tile 0 -> buf 0
    int cur = 0;
    for (int t = 0; t < 16; ++t) {
        __syncthreads();                   // stage of tile t complete (vmcnt0)
        if (t < 15) QSTAGE((t + 1) << 6, cur ^ 1);
#pragma unroll
        for (int ks = 0; ks < 2; ++ks) {
            f16x8 af[2], bf[4];
#pragma unroll
            for (int i = 0; i < 2; ++i) {
                const int r = wave*32 + i*16 + l15;
                af[i] = *(const f16x8*)&As[cur][(r << 6) + ((((ks<<2)+quad) ^ (l15 & 7)) << 3)];
            }
#pragma unroll
            for (int j = 0; j < 4; ++j) {
                const int r = j*16 + l15;
                bf[j] = *(const f16x8*)&Bs[cur][(r << 6) + ((((ks<<2)+quad) ^ (l15 & 7)) << 3)];
            }
#pragma unroll
            for (int i = 0; i < 2; ++i)
#pragma unroll
                for (int j = 0; j < 4; ++j)
                    acc[i][j] = MFMA16(af[i], bf[j], acc[i][j]);
        }
        cur ^= 1;
    }
#undef QSTAGE

    float bv[4];
#pragma unroll
    for (int j = 0; j < 4; ++j) bv[j] = bias[n0 + j*16 + l15];

    if (which == 2) {
        // ---- fused v-transpose via LDS bounce ----
        __syncthreads();                   // all waves done with K-loop LDS
        f16* T = &As[0][0];                // [64 d][136 s-padded], 17.4 KB
        const int b  = m0 >> 11, s0 = m0 & (SS - 1);
        const int bhv = b*HH + h;
        float colsum[4];
#pragma unroll
        for (int j = 0; j < 4; ++j) {
            colsum[j] = 0.f;
#pragma unroll
            for (int i = 0; i < 2; ++i) {
                f16x4 pk;
#pragma unroll
                for (int reg = 0; reg < 4; ++reg) {
                    const f16 hv = (f16)(acc[i][j][reg] + bv[j]);
                    pk[reg] = hv;
                    colsum[j] += (float)hv;   // f16-rounded, matches vtrans
                }
                const int m_loc = wave*32 + i*16 + quad*4;
                *(f16x4*)&T[(j*16 + l15)*136 + m_loc] = pk;
            }
        }
#pragma unroll
        for (int j = 0; j < 4; ++j) {
            float c = colsum[j];
            c += __shfl_xor(c, 16, 64);       // reduce over quads
            c += __shfl_xor(c, 32, 64);
            if (quad == 0)
                atomicAdd(vmean + bhv*DD_ + j*16 + l15, c * (1.f / SS));
        }
        __syncthreads();
        const int d = tid >> 2, ch = (tid & 3) << 5;   // 32 s-elems/thread
        f16* dp = vtb + ((size_t)(bhv*DD_ + d))*SS + s0 + ch;
#pragma unroll
        for (int u = 0; u < 4; ++u)
            *(f16x8*)(dp + u*8) = *(const f16x8*)&T[d*136 + ch + u*8];
        return;
    }

    const float scale = (which == 0) ? LOG2E : 1.f;
    f16* __restrict__ dst = (which == 0) ? q16 : k16;
#pragma unroll
    for (int i = 0; i < 2; ++i) {
#pragma unroll
        for (int reg = 0; reg < 4; ++reg) {
            const int m = m0 + wave*32 + i*16 + quad*4 + reg;
            const int b = m >> 11, s = m & (SS - 1);
            f16* rowp = dst + (((size_t)(b*HH + h))*SS + s)*DD_ + l15;
#pragma unroll
            for (int j = 0; j < 4; ++j)
                rowp[j*16] = (f16)((acc[i][j][reg] + bv[j]) * scale);
        }
    }
}

// ---------------------------------------------------------------------------
// Flash attention v12 (verified r6-r11, best config: PARTS=4). PARTS=8
// regressed 3x (r12): 128MB opart exceeded L3 retention -> partials spilled
// to HBM (FETCH 6->88MB, WRITE 25->165MB, MfmaUtil 5.9). PARTS=4 is the
// sweet spot between occupancy and L3 capacity.
// x = qc*PARTS+kp (uniform mod 8), y = bh (slow). 2-phase dbuf LDS,
// prefetch t+1, defer-max, register P^T reshape, setprio.
// ---------------------------------------------------------------------------
template<int KPL>
__global__ __launch_bounds__(256, 4) void attn_kernel(
    const f16* __restrict__ q16, const f16* __restrict__ k16,
    const f16* __restrict__ vt,
    const float* __restrict__ gates, const float* __restrict__ imp,
    const float* __restrict__ thr,
    float* __restrict__ opart, float* __restrict__ mlpart)
{
    constexpr int NT = 1 << (5 - KPL);     // 64-key tiles per part
    __shared__ f16 Ks[2][64*64];
    __shared__ f16 Vs[2][64*64];
    const int tid  = threadIdx.x;
    const int wave = tid >> 6, lane = tid & 63;
    const int l31 = lane & 31, hi = lane >> 5, l7 = lane & 7;
    const int bh = blockIdx.y;             // SLOW dim: id%8 independent of bh
    const int kp = blockIdx.x & ((1 << KPL) - 1);
    const int qc = blockIdx.x >> KPL;      // 0..15
    const int q0 = qc << 7;                // 128 q-rows/block
    const int k0 = kp << (11 - KPL);       // keys/part = SS>>KPL

    if (!head_active(gates, imp, thr, bh & (HH - 1))) return;

    const f16* qb = q16 + (size_t)bh * SS * DD_;
    const f16* kb = k16 + (size_t)bh * SS * DD_;
    const f16* vb = vt  + (size_t)bh * DD_ * SS;

    // staging (r6 pattern): thread owns chunks tid, tid+256 of each tile
    const int r0 = tid >> 3, r1 = r0 + 32, cc = tid & 7;
    const int sc0 = (cc ^ (r0 & 7)) << 3;
    const int sc1 = (cc ^ (r1 & 7)) << 3;

    // prologue: stage tile 0 into buffer 0 (flies under Q-frag loads)
    gload16(kb + (size_t)(k0 + r0)*DD_ + sc0, &Ks[0][tid << 3]);
    gload16(kb + (size_t)(k0 + r1)*DD_ + sc1, &Ks[0][(tid + 256) << 3]);
    gload16(vb + (size_t)r0*SS + k0 + sc0,    &Vs[0][tid << 3]);
    gload16(vb + (size_t)r1*SS + k0 + sc1,    &Vs[0][(tid + 256) << 3]);

    f16x8 qf[4];
#pragma unroll
    for (int ks = 0; ks < 4; ++ks)
        qf[ks] = *(const f16x8*)(qb +
            (size_t)(q0 + wave*32 + l31)*DD_ + ks*16 + hi*8);

    f32x16 accO[2];
#pragma unroll
    for (int dt = 0; dt < 2; ++dt)
#pragma unroll
        for (int r = 0; r < 16; ++r) accO[dt][r] = 0.f;
    float M = 0.f;
    float lsum = 0.f;

    int cur = 0;
    for (int t = 0; t < NT; ++t) {
        const int kt = k0 + (t << 6);
        __syncthreads();               // stage of tile t complete (vmcnt0)
        if (t < NT - 1) {              // prefetch tile t+1 into other buffer
            const int kn = kt + 64;
            gload16(kb + (size_t)(kn + r0)*DD_ + sc0, &Ks[cur^1][tid << 3]);
            gload16(kb + (size_t)(kn + r1)*DD_ + sc1, &Ks[cur^1][(tid + 256) << 3]);
            gload16(vb + (size_t)r0*SS + kn + sc0,    &Vs[cur^1][tid << 3]);
            gload16(vb + (size_t)r1*SS + kn + sc1,    &Vs[cur^1][(tid + 256) << 3]);
        }

        // S^T[key][qrow] - M: A = K rows, B = Q^T, C init = -M
        f32x16 accS[2];
        const float negM = -M;
#pragma unroll
        for (int mt = 0; mt < 2; ++mt)
#pragma unroll
            for (int r = 0; r < 16; ++r) accS[mt][r] = negM;
        __builtin_amdgcn_s_setprio(1);
#pragma unroll
        for (int ks = 0; ks < 4; ++ks)
#pragma unroll
            for (int mt = 0; mt < 2; ++mt) {
                f16x8 kf = *(const f16x8*)&Ks[cur][((mt*32 + l31) << 6) +
                                                  ((((ks<<1)+hi) ^ l7) << 3)];
                accS[mt] = MFMA32(kf, qf[ks], accS[mt]);
            }
        __builtin_amdgcn_s_setprio(0);

        // defer-max
        const float mxl = fmaxf(vmax16(accS[0]), vmax16(accS[1]));
        if (!__all(mxl <= 8.f)) {
            float mx = mxl;
            mx = fmaxf(mx, __shfl_xor(mx, 1, 64));
            mx = fmaxf(mx, __shfl_xor(mx, 2, 64));
            mx = fmaxf(mx, __shfl_xor(mx, 4, 64));
            mx = fmaxf(mx, __shfl_xor(mx, 8, 64));
            mx = fmaxf(mx, __shfl_xor(mx, 16, 64));
            mx = fmaxf(mx, __shfl_xor(mx, 32, 64));
            const float alpha = EXP2F(-mx);
            M += mx;
            lsum *= alpha;
#pragma unroll
            for (int r = 0; r < 16; ++r) { accO[0][r] *= alpha; accO[1][r] *= alpha; }
#pragma unroll
            for (int mt = 0; mt < 2; ++mt)
#pragma unroll
                for (int r = 0; r < 16; ++r) accS[mt][r] -= mx;
        }

        // p = exp2(accS); per-row sums
        float rs[2];
#pragma unroll
        for (int mt = 0; mt < 2; ++mt) {
            float t0 = 0.f, t1 = 0.f, t2 = 0.f, t3 = 0.f;
#pragma unroll
            for (int r = 0; r < 16; r += 4) {
                float p0 = EXP2F(accS[mt][r+0]); accS[mt][r+0] = p0; t0 += p0;
                float p1 = EXP2F(accS[mt][r+1]); accS[mt][r+1] = p1; t1 += p1;
                float p2 = EXP2F(accS[mt][r+2]); accS[mt][r+2] = p2; t2 += p2;
                float p3 = EXP2F(accS[mt][r+3]); accS[mt][r+3] = p3; t3 += p3;
            }
            rs[mt] = (t0 + t1) + (t2 + t3);
        }
        float sum = rs[0] + rs[1];
        sum += __shfl_xor(sum, 32, 64);
        lsum += sum;

        // pack P to f16x2 pairs
        int pki[2][8];
#pragma unroll
        for (int mt = 0; mt < 2; ++mt)
#pragma unroll
            for (int t2_ = 0; t2_ < 8; ++t2_) {
                union { fp16x2 h; int i; } c;
                c.h = __builtin_amdgcn_cvt_pkrtz(accS[mt][2*t2_], accS[mt][2*t2_+1]);
                pki[mt][t2_] = c.i;
            }

        // PV: O^T = V^T * P^T (r8-verified B-frag mapping)
#pragma unroll
        for (int ks = 0; ks < 4; ++ks) {
            const int mt = ks >> 1;
            const int bidx = (ks & 1) << 2;
            const int a0 = pki[mt][bidx+0], a1 = pki[mt][bidx+1];
            const int b0 = pki[mt][bidx+2], b1 = pki[mt][bidx+3];
            const int s0 = hi ? a0 : b0;
            const int s1 = hi ? a1 : b1;
            const int r0x = __shfl_xor(s0, 32, 64);
            const int r1x = __shfl_xor(s1, 32, 64);
            union { int i[4]; f16x8 h; } u;
            u.i[0] = hi ? r0x : a0;
            u.i[1] = hi ? r1x : a1;
            u.i[2] = hi ? b0 : r0x;
            u.i[3] = hi ? b1 : r1x;
            f16x8 pf = u.h;
            __builtin_amdgcn_s_setprio(1);
#pragma unroll
            for (int dt = 0; dt < 2; ++dt) {
                f16x8 vf = *(const f16x8*)&Vs[cur][((dt*32 + l31) << 6) +
                                                  ((((ks<<1)+hi) ^ l7) << 3)];
                accO[dt] = MFMA32(vf, pf, accO[dt]);
            }
            __builtin_amdgcn_s_setprio(0);
        }
        cur ^= 1;
    }

    // store fp32 partials: O^T (un-normalized), M, lsum per q-row
    {
        const int s = q0 + wave*32 + l31;
        const size_t rowi = (size_t)kp*BH*SS + (size_t)bh*SS + s;
        float* ob = opart + (rowi << 6);
#pragma unroll
        for (int dt = 0; dt < 2; ++dt)
#pragma unroll
            for (int g = 0; g < 4; ++g) {
                const int d0 = dt*32 + 8*g + 4*hi;
                float4 o = { accO[dt][4*g+0], accO[dt][4*g+1],
                             accO[dt][4*g+2], accO[dt][4*g+3] };
                *(float4*)(ob + d0) = o;
            }
        if (hi == 0) {
            float2 ml = { M, lsum };
            *(float2*)(mlpart + rowi*2) = ml;
        }
    }
}

// ---------------------------------------------------------------------------
// Combine PARTS key-part partials. Inactive heads: return WITHOUT writing.
// ---------------------------------------------------------------------------
template<int PARTS>
__global__ __launch_bounds__(256) void combine_kernel(
    const float* __restrict__ opart, const float* __restrict__ mlpart,
    const float* __restrict__ vmean,
    const float* __restrict__ gates, const float* __restrict__ imp,
    const float* __restrict__ thr, f16* __restrict__ aout)
{
    const int t = blockIdx.x * 256 + threadIdx.x;  // 0 .. 262143
    const int row = t >> 2;                        // bh*SS + s
    const int dc = (t & 3) << 4;
    const int bh = row >> 11, s = row & (SS - 1);
    const int b = bh >> 4, h = bh & (HH - 1);

    if (!head_active(gates, imp, thr, h)) return;  // aout region never read

    f16* op = aout + ((size_t)(b*SS + s))*EE + h*DD_ + dc;
    float2 ml[PARTS];
    float mx = -1.0e30f;
#pragma unroll
    for (int p = 0; p < PARTS; ++p) {
        ml[p] = ((const float2*)mlpart)[(size_t)p*BH*SS + row];
        mx = fmaxf(mx, ml[p].x);
    }
    float a[PARTS], denom = 0.f;
#pragma unroll
    for (int p = 0; p < PARTS; ++p) {
        a[p] = EXP2F(ml[p].x - mx);
        denom += ml[p].y * a[p];
    }
    const float inv = 1.f / denom;
    const float* o0 = opart + ((size_t)row << 6) + dc;
#pragma unroll
    for (int j = 0; j < 4; ++j) {
        float4 acc = {0.f, 0.f, 0.f, 0.f};
#pragma unroll
        for (int p = 0; p < PARTS; ++p) {
            float4 v = ((const float4*)(o0 + (size_t)p*BH*SS*DD_))[j];
            acc.x += v.x*a[p]; acc.y += v.y*a[p];
            acc.z += v.z*a[p]; acc.w += v.w*a[p];
        }
        float4 vm = *(const float4*)(vmean + bh*DD_ + dc + 4*j);
        f16x4 o = { (f16)(acc.x*inv + vm.x), (f16)(acc.y*inv + vm.y),
                    (f16)(acc.z*inv + vm.z), (f16)(acc.w*inv + vm.w) };
        *(f16x4*)(op + 4*j) = o;
    }
}

// ---------------------------------------------------------------------------
// Output GEMM v3 (verified r11): K-tile skip + 2-phase dbuf over the active
// K-tile list, 64-row M-blocks (512 blocks = 2/CU). LDS 48 KB.
// ---------------------------------------------------------------------------
__global__ __launch_bounds__(256) void out_gemm_kernel(
    const f16* __restrict__ a, const f16* __restrict__ w,
    const float* __restrict__ bias, const float* __restrict__ gates,
    const float* __restrict__ imp, const float* __restrict__ thr,
    float* __restrict__ y)
{
    __shared__ f16 As[2][64*64];
    __shared__ f16 Bs[2][128*64];
    const int tid  = threadIdx.x;
    const int wave = tid >> 6, lane = tid & 63;
    const int quad = lane >> 4, l15 = lane & 15;
    const int wm = wave & 1, wn = wave >> 1;
    const int m0 = blockIdx.x << 6;        // 64-row block (fast, XCD-uniform)
    const int n0 = blockIdx.y << 7;

    unsigned hmask = 0;
#pragma unroll
    for (int h = 0; h < HH; ++h)
        if (head_active(gates, imp, thr, h)) hmask |= (1u << h);

#define OSTAGE(K0, B) do {                                                   \
    _Pragma("unroll")                                                        \
    for (int u = 0; u < 2; ++u) {          /* As: 64x64 = 8 KB */            \
        const int s_ = tid + (u << 8);                                       \
        const int r_ = s_ >> 3;                                              \
        const int sc_ = ((s_ & 7) ^ (r_ & 7)) << 3;                          \
        gload16(a + (size_t)(m0 + r_)*EE + (K0) + sc_, &As[B][s_ << 3]);     \
    }                                                                        \
    _Pragma("unroll")                                                        \
    for (int u = 0; u < 4; ++u) {          /* Bs: 128x64 = 16 KB */          \
        const int s_ = tid + (u << 8);                                       \
        const int r_ = s_ >> 3;                                              \
        const int sc_ = ((s_ & 7) ^ (r_ & 7)) << 3;                          \
        gload16(w + (size_t)(n0 + r_)*EE + (K0) + sc_, &Bs[B][s_ << 3]);     \
    } } while (0)

    f32x4 acc[2][4];
#pragma unroll
    for (int i = 0; i < 2; ++i)
#pragma unroll
        for (int j = 0; j < 4; ++j) acc[i][j] = (f32x4){0.f,0.f,0.f,0.f};

    unsigned m = hmask;
    int kcur = m ? (__ffs(m) - 1) : -1;
    if (m) m &= m - 1;
    if (kcur >= 0) OSTAGE(kcur << 6, 0);
    int cur = 0;
    while (kcur >= 0) {
        const int knext = m ? (__ffs(m) - 1) : -1;
        if (m) m &= m - 1;
        __syncthreads();                   // stage into cur complete (vmcnt0)
        if (knext >= 0) OSTAGE(knext << 6, cur ^ 1);
#pragma unroll
        for (int ks = 0; ks < 2; ++ks) {
            f16x8 af[2], bf[4];
#pragma unroll
            for (int i = 0; i < 2; ++i) {
                const int r = wm*32 + i*16 + l15;
                af[i] = *(const f16x8*)&As[cur][(r << 6) + ((((ks<<2)+quad) ^ (l15 & 7)) << 3)];
            }
#pragma unroll
            for (int j = 0; j < 4; ++j) {
                const int r = wn*64 + j*16 + l15;
                bf[j] = *(const f16x8*)&Bs[cur][(r << 6) + ((((ks<<2)+quad) ^ (l15 & 7)) << 3)];
            }
#pragma unroll
            for (int i = 0; i < 2; ++i)
#pragma unroll
                for (int j = 0; j < 4; ++j)
                    acc[i][j] = MFMA16(af[i], bf[j], acc[i][j]);
        }
        cur ^= 1;
        kcur = knext;
    }
#undef OSTAGE

    float bv[4];
#pragma unroll
    for (int j = 0; j < 4; ++j) bv[j] = bias[n0 + wn*64 + j*16 + l15];
#pragma unroll
    for (int i = 0; i < 2; ++i) {
#pragma unroll
        for (int reg = 0; reg < 4; ++reg) {
            const int m2 = m0 + wm*32 + i*16 + quad*4 + reg;
#pragma unroll
            for (int j = 0; j < 4; ++j)
                y[(size_t)m2*EE + n0 + wn*64 + j*16 + l15] = acc[i][j][reg] + bv[j];
        }
    }
}

// ---------------------------------------------------------------------------
extern "C" void kernel_launch(void* const* d_in, const int* in_sizes, int n_in,
                              void* d_out, int out_size, void* d_ws, size_t ws_size,
                              hipStream_t stream)
{
    const float* x      = (const float*)d_in[0];
    const float* qkv_w  = (const float*)d_in[1];
    const float* qkv_b  = (const float*)d_in[2];
    const float* out_w  = (const float*)d_in[3];
    const float* out_b  = (const float*)d_in[4];
    const float* gates  = (const float*)d_in[5];
    const float* imp    = (const float*)d_in[6];
    const float* thr    = (const float*)d_in[7];
    float* out = (float*)d_out;

    const size_t TSZ = (size_t)BH * SS * DD_;
    f16* x16  = (f16*)d_ws;
    f16* w116 = x16 + (size_t)MROWS * EE;
    f16* w216 = w116 + (size_t)NQKV * EE;
    f16* q16  = w216 + (size_t)EE * EE;
    f16* k16  = q16 + TSZ;
    f16* vtb  = k16 + TSZ;                 // v16 eliminated (fused vtrans)
    f16* aout = vtb + TSZ;
    float* vmean  = (float*)(aout + TSZ);               // BH*DD_ floats
    float* opart  = vmean + (size_t)BH * DD_;

    // key-split: 4 parts if workspace allows, else 2. (8 parts regressed:
    // 128MB partials exceed L3 retention -> HBM spill, r12.)
    const size_t base_bytes = (size_t)((char*)opart - (char*)d_ws);
    const size_t per_part   = (size_t)BH*SS*DD_*4 + (size_t)BH*SS*2*4;
    const int parts = (ws_size >= base_bytes + 4*per_part) ? 4 : 2;

    float* mlpart = opart + (size_t)parts*BH*SS*DD_;

    cvt_kernel<<<(NX4 + NW14 + NW24) / 256, 256, 0, stream>>>(
        x, qkv_w, out_w, x16, w116, w216, gates, imp, thr, vmean);

    dim3 g1(MROWS/128, NQKV/64);    // 32 x 48: rows fast (XCD-uniform)
    qkv_gemm_kernel<<<g1, 256, 0, stream>>>(x16, w116, qkv_b, gates, imp, thr,
                                            q16, k16, vtb, vmean);

    // x = (qc,kp) fast -> id%8 uniform over XCDs; bh SLOW
    dim3 g2a(16 * parts, BH);
    if (parts == 4)
        attn_kernel<2><<<g2a, 256, 0, stream>>>(q16, k16, vtb, gates, imp, thr,
                                                opart, mlpart);
    else
        attn_kernel<1><<<g2a, 256, 0, stream>>>(q16, k16, vtb, gates, imp, thr,
                                                opart, mlpart);

    if (parts == 4)
        combine_kernel<4><<<(BH*SS*4)/256, 256, 0, stream>>>(
            opart, mlpart, vmean, gates, imp, thr, aout);
    else
        combine_kernel<2><<<(BH*SS*4)/256, 256, 0, stream>>>(
            opart, mlpart, vmean, gates, imp, thr, aout);

    dim3 g3(MROWS/64, EE/128);      // 64 x 8: 64-row blocks, rows fast
    out_gemm_kernel<<<g3, 256, 0, stream>>>(aout, w216, out_b, gates, imp, thr,
                                            out);
}